// Round 3
// baseline (893.217 us; speedup 1.0000x reference)
//
#include <hip/hip_runtime.h>
#include <hip/hip_bf16.h>
#include <stdint.h>
#include <stddef.h>

typedef __bf16 bf16;
typedef __bf16 bf16x8 __attribute__((ext_vector_type(8)));
typedef float f32x4 __attribute__((ext_vector_type(4)));
typedef __attribute__((address_space(1))) void gvoid;
typedef __attribute__((address_space(3))) void lvoid;

#define BM 128
#define BN 128
#define BK 32

// fp32 -> bf16 elementwise convert, 8 elements/thread
__global__ __launch_bounds__(256)
void cvt_f32_bf16(const float* __restrict__ in, bf16* __restrict__ out, int n8)
{
    int i = blockIdx.x * 256 + threadIdx.x;
    if (i >= n8) return;
    const f32x4* p = (const f32x4*)in + (size_t)i * 2;
    f32x4 a = p[0], b = p[1];
    bf16x8 o;
    o[0] = (bf16)a[0]; o[1] = (bf16)a[1]; o[2] = (bf16)a[2]; o[3] = (bf16)a[3];
    o[4] = (bf16)b[0]; o[5] = (bf16)b[1]; o[6] = (bf16)b[2]; o[7] = (bf16)b[3];
    *((bf16x8*)out + i) = o;
}

// C[M,N] = act(A[M,K] * B[N,K]^T + bias1 (+ bias2)); A,B bf16 row-major,
// biases fp32, fp32 MFMA accumulation, output bf16 or fp32.
// 1-D grid with XCD-aware swizzle: xcd = blockIdx&7 owns bn strip of
// 2^log2cpx columns -> B panel (<=1 MB) stays resident in that XCD's L2.
// Requires M%128==0, N%128==0, K%32==0, (N/128)%8==0 handled by host.
template<int RELU, int TWO_BIAS, int OUTF32>
__global__ __launch_bounds__(256, 2)
void gemm_bt(const bf16* __restrict__ A, const bf16* __restrict__ Bm,
             const float* __restrict__ bias1, const float* __restrict__ bias2,
             void* __restrict__ Cp, int M, int N, int K, int log2cpx)
{
    // Linear row-major tiles: global_load_lds writes wave-uniform base + lane*16,
    // so NO padding (m104/m108 caveat).
    __shared__ __align__(16) bf16 As[BM * BK];
    __shared__ __align__(16) bf16 Bs[BN * BK];

    const int tid  = threadIdx.x;
    const int wave = tid >> 6;
    const int lane = tid & 63;

    // XCD swizzle: blocks round-robin XCDs by linear id (m09 heuristic).
    const unsigned b  = blockIdx.x;
    const int xcd     = b & 7;
    const unsigned li = b >> 3;
    const int bn = (xcd << log2cpx) + (int)(li & ((1u << log2cpx) - 1u));
    const int bm = (int)(li >> log2cpx);

    // 2x2 waves, each owns a 64x64 sub-tile (4x4 of 16x16 MFMA tiles)
    const int wm = (wave >> 1) * 64;
    const int wn = (wave & 1) * 64;

    // ---- staging: each wave stages two 16-row x 32-col chunks (1 KiB each)
    const int r_in = lane >> 2;
    const int c8   = (lane & 3) * 8;
    const int ch0  = wave * 2;

    const bf16* aG0 = A  + (size_t)(bm * BM + (ch0 + 0) * 16 + r_in) * K + c8;
    const bf16* aG1 = A  + (size_t)(bm * BM + (ch0 + 1) * 16 + r_in) * K + c8;
    const bf16* bG0 = Bm + (size_t)(bn * BN + (ch0 + 0) * 16 + r_in) * K + c8;
    const bf16* bG1 = Bm + (size_t)(bn * BN + (ch0 + 1) * 16 + r_in) * K + c8;

    bf16* aL0 = &As[(ch0 + 0) * 512];
    bf16* aL1 = &As[(ch0 + 1) * 512];
    bf16* bL0 = &Bs[(ch0 + 0) * 512];
    bf16* bL1 = &Bs[(ch0 + 1) * 512];

    // ---- MFMA fragment addressing (16x16x32 bf16):
    // A-op: lane holds A[m = lane&15][k = (lane>>4)*8 + j]; B^T: same form.
    const int frow = lane & 15;
    const int fk   = (lane >> 4) * 8;
    const int aOff = (wm + frow) * BK + fk;
    const int bOff = (wn + frow) * BK + fk;

    f32x4 acc[4][4];
    #pragma unroll
    for (int i = 0; i < 4; i++)
        #pragma unroll
        for (int j = 0; j < 4; j++)
            acc[i][j] = {0.f, 0.f, 0.f, 0.f};

    for (int k0 = 0; k0 < K; k0 += BK) {
        __builtin_amdgcn_global_load_lds((gvoid*)aG0, (lvoid*)aL0, 16, 0, 0);
        __builtin_amdgcn_global_load_lds((gvoid*)aG1, (lvoid*)aL1, 16, 0, 0);
        __builtin_amdgcn_global_load_lds((gvoid*)bG0, (lvoid*)bL0, 16, 0, 0);
        __builtin_amdgcn_global_load_lds((gvoid*)bG1, (lvoid*)bL1, 16, 0, 0);
        aG0 += BK; aG1 += BK; bG0 += BK; bG1 += BK;
        __syncthreads();   // drains vmcnt(0) before s_barrier

        bf16x8 af[4], bfr[4];
        #pragma unroll
        for (int i = 0; i < 4; i++)
            af[i] = *(const bf16x8*)&As[aOff + i * 16 * BK];
        #pragma unroll
        for (int j = 0; j < 4; j++)
            bfr[j] = *(const bf16x8*)&Bs[bOff + j * 16 * BK];

        #pragma unroll
        for (int i = 0; i < 4; i++)
            #pragma unroll
            for (int j = 0; j < 4; j++)
                acc[i][j] = __builtin_amdgcn_mfma_f32_16x16x32_bf16(
                    af[i], bfr[j], acc[i][j], 0, 0, 0);

        __syncthreads();   // protect LDS before next stage overwrites
    }

    // ---- epilogue: C/D layout col=lane&15, row=(lane>>4)*4+reg (m89/m91)
    const int crow0 = bm * BM + wm + (lane >> 4) * 4;
    const int ccol0 = bn * BN + wn + (lane & 15);

    #pragma unroll
    for (int j = 0; j < 4; j++) {
        const int col = ccol0 + j * 16;
        float bv = bias1[col];
        if (TWO_BIAS) bv += bias2[col];
        #pragma unroll
        for (int i = 0; i < 4; i++) {
            const int row = crow0 + i * 16;
            #pragma unroll
            for (int r = 0; r < 4; r++) {
                float v = acc[i][j][r] + bv;
                if (RELU) v = fmaxf(v, 0.0f);
                if (OUTF32)
                    ((float*)Cp)[(size_t)(row + r) * N + col] = v;
                else
                    ((bf16*)Cp)[(size_t)(row + r) * N + col] = (bf16)v;
            }
        }
    }
}

static inline int cvt_blocks(size_t n) { return (int)((n / 8 + 255) / 256); }

extern "C" void kernel_launch(void* const* d_in, const int* in_sizes, int n_in,
                              void* d_out, int out_size, void* d_ws, size_t ws_size,
                              hipStream_t stream) {
    const float* x       = (const float*)d_in[0];  // [B,S,D_IN] fp32
    const float* W_init  = (const float*)d_in[1];  // [D_H, D_IN] fp32
    const float* b_init  = (const float*)d_in[2];  // [D_H] fp32
    const float* W_ih    = (const float*)d_in[3];  // [D_H, D_H] fp32
    const float* b_ih    = (const float*)d_in[4];  // [D_H] fp32
    const float* b_hh    = (const float*)d_in[5];  // [D_H] fp32
    const float* W_final = (const float*)d_in[6];  // [D_ACT, D_H] fp32
    const float* b_final = (const float*)d_in[7];  // [D_ACT] fp32
    float* out = (float*)d_out;                    // [B,S,D_ACT] fp32

    const int D_H   = in_sizes[2];               // 2048
    const int D_IN  = in_sizes[1] / D_H;         // 1024
    const int D_ACT = in_sizes[7];               // 1024
    const int M     = in_sizes[0] / D_IN;        // B*S = 32768

    const size_t nx  = (size_t)M * D_IN;
    const size_t nw1 = (size_t)D_H * D_IN;
    const size_t nw2 = (size_t)D_H * D_H;
    const size_t nw3 = (size_t)D_ACT * D_H;
    const size_t nh  = (size_t)M * D_H;

    // ws layout: [h: nh*2][a2: nh*2][w1b][w2b][w3b]; xb aliases a2's region
    // (x is dead before layer 2 writes a2 — same-stream ordering).
    char* ws  = (char*)d_ws;
    bf16* h   = (bf16*)ws;
    bf16* a2  = (bf16*)(ws + nh * 2);
    bf16* xb  = a2;                               // alias, see above
    bf16* w1b = (bf16*)(ws + nh * 4);
    bf16* w2b = w1b + nw1;
    bf16* w3b = w2b + nw2;

    cvt_f32_bf16<<<cvt_blocks(nx),  256, 0, stream>>>(x,       xb,  (int)(nx  / 8));
    cvt_f32_bf16<<<cvt_blocks(nw1), 256, 0, stream>>>(W_init,  w1b, (int)(nw1 / 8));
    cvt_f32_bf16<<<cvt_blocks(nw2), 256, 0, stream>>>(W_ih,    w2b, (int)(nw2 / 8));
    cvt_f32_bf16<<<cvt_blocks(nw3), 256, 0, stream>>>(W_final, w3b, (int)(nw3 / 8));

    dim3 blk(256);
    // log2cpx = log2((N/BN)/8): #bn columns per XCD (pow2 for our shapes)
    const int l2c_2048 = 1;   // N=2048: 16 bn cols, 2 per XCD -> 1 MB B panel
    const int l2c_1024 = 0;   // N=1024:  8 bn cols, 1 per XCD -> 0.5 MB

    // layer 1: h = relu(x @ W_init^T + b_init)          [bf16 out]
    gemm_bt<1, 0, 0><<<dim3((M / BM) * (D_H / BN)), blk, 0, stream>>>(
        xb, w1b, b_init, nullptr, h, M, D_H, D_IN, l2c_2048);

    // layer 2: a2 = relu(h @ W_ih^T + b_ih + b_hh)      [bf16 out]
    gemm_bt<1, 1, 0><<<dim3((M / BM) * (D_H / BN)), blk, 0, stream>>>(
        h, w2b, b_ih, b_hh, a2, M, D_H, D_H, l2c_2048);

    // layer 3: out = a2 @ W_final^T + b_final           [fp32 out]
    gemm_bt<0, 0, 1><<<dim3((M / BM) * (D_ACT / BN)), blk, 0, stream>>>(
        a2, w3b, b_final, nullptr, out, M, D_ACT, D_H, l2c_1024);
}

// Round 4
// 806.642 us; speedup vs baseline: 1.1073x; 1.1073x over previous
//
#include <hip/hip_runtime.h>
#include <hip/hip_bf16.h>
#include <stdint.h>
#include <stddef.h>

typedef __bf16 bf16;
typedef __bf16 bf16x8 __attribute__((ext_vector_type(8)));
typedef float f32x4 __attribute__((ext_vector_type(4)));
typedef __attribute__((address_space(1))) void gvoid;
typedef __attribute__((address_space(3))) void lvoid;

#define BM 128
#define BN 128
#define BK 64

// fp32 -> bf16 elementwise convert, 8 elements/thread
__global__ __launch_bounds__(256)
void cvt_f32_bf16(const float* __restrict__ in, bf16* __restrict__ out, int n8)
{
    int i = blockIdx.x * 256 + threadIdx.x;
    if (i >= n8) return;
    const f32x4* p = (const f32x4*)in + (size_t)i * 2;
    f32x4 a = p[0], b = p[1];
    bf16x8 o;
    o[0] = (bf16)a[0]; o[1] = (bf16)a[1]; o[2] = (bf16)a[2]; o[3] = (bf16)a[3];
    o[4] = (bf16)b[0]; o[5] = (bf16)b[1]; o[6] = (bf16)b[2]; o[7] = (bf16)b[3];
    *((bf16x8*)out + i) = o;
}

// C[M,N] = act(A[M,K] * B[N,K]^T + bias1 (+ bias2)); A,B bf16 row-major,
// biases fp32, fp32 MFMA accumulation, output bf16 or fp32.
// BK=64 tiles with XOR-granule LDS swizzle:
//   LDS row r (128 B = 32 banks) stores global k-granule g (16 B) at slot
//   g ^ (r & 7). Applied on the GLOBAL address side because global_load_lds
//   forces dest = wave-uniform base + lane*16 (m104/m108). ds_reads XOR back.
//   -> quarter-wave fragment reads spread over all 8 bank-groups: 2-way only
//   (free, m136), vs ~8-way at the old linear BK=32 layout.
// Requires M%128==0, N%128==0, K%64==0.
template<int RELU, int TWO_BIAS, int OUTF32>
__global__ __launch_bounds__(256, 2)
void gemm_bt(const bf16* __restrict__ A, const bf16* __restrict__ Bm,
             const float* __restrict__ bias1, const float* __restrict__ bias2,
             void* __restrict__ Cp, int M, int N, int K)
{
    __shared__ __align__(16) bf16 As[BM * BK];   // 16 KiB, linear [128][64]
    __shared__ __align__(16) bf16 Bs[BN * BK];   // 16 KiB

    const int tid  = threadIdx.x;
    const int wave = tid >> 6;
    const int lane = tid & 63;
    const int bn = blockIdx.x;
    const int bm = blockIdx.y;

    // 2x2 waves, each owns a 64x64 sub-tile (4x4 of 16x16 MFMA tiles)
    const int wm = (wave >> 1) * 64;
    const int wn = (wave & 1) * 64;

    // ---- staging: chunk = 8 rows x 64 cols (1 KiB). 16 chunks per matrix;
    // each wave stages chunks [wave*4, wave*4+4) of A and of B.
    // lane l -> row l>>3, k-granule (l&7) XOR (row&7)  (swizzle, see above)
    const int r_in = lane >> 3;                    // 0..7
    const int c8   = (((lane & 7) ^ r_in)) * 8;    // swizzled global k-offset
    const int ch0  = wave * 4;

    const bf16* aG0 = A  + (size_t)(bm * BM + (ch0 + 0) * 8 + r_in) * K + c8;
    const bf16* aG1 = A  + (size_t)(bm * BM + (ch0 + 1) * 8 + r_in) * K + c8;
    const bf16* aG2 = A  + (size_t)(bm * BM + (ch0 + 2) * 8 + r_in) * K + c8;
    const bf16* aG3 = A  + (size_t)(bm * BM + (ch0 + 3) * 8 + r_in) * K + c8;
    const bf16* bG0 = Bm + (size_t)(bn * BN + (ch0 + 0) * 8 + r_in) * K + c8;
    const bf16* bG1 = Bm + (size_t)(bn * BN + (ch0 + 1) * 8 + r_in) * K + c8;
    const bf16* bG2 = Bm + (size_t)(bn * BN + (ch0 + 2) * 8 + r_in) * K + c8;
    const bf16* bG3 = Bm + (size_t)(bn * BN + (ch0 + 3) * 8 + r_in) * K + c8;

    bf16* aL0 = &As[(ch0 + 0) * 512];
    bf16* aL1 = &As[(ch0 + 1) * 512];
    bf16* aL2 = &As[(ch0 + 2) * 512];
    bf16* aL3 = &As[(ch0 + 3) * 512];
    bf16* bL0 = &Bs[(ch0 + 0) * 512];
    bf16* bL1 = &Bs[(ch0 + 1) * 512];
    bf16* bL2 = &Bs[(ch0 + 2) * 512];
    bf16* bL3 = &Bs[(ch0 + 3) * 512];

    // ---- MFMA fragment addressing (16x16x32 bf16):
    // lane holds A[m = lane&15][k = 32*h + (lane>>4)*8 + j], h = K-half.
    // LDS slot of global granule g for row r is g ^ (r&7).
    const int frow = lane & 15;
    const int g0   = lane >> 4;        // 0..3
    const int fsw  = frow & 7;

    f32x4 acc[4][4];
    #pragma unroll
    for (int i = 0; i < 4; i++)
        #pragma unroll
        for (int j = 0; j < 4; j++)
            acc[i][j] = {0.f, 0.f, 0.f, 0.f};

    for (int k0 = 0; k0 < K; k0 += BK) {
        __builtin_amdgcn_global_load_lds((gvoid*)aG0, (lvoid*)aL0, 16, 0, 0);
        __builtin_amdgcn_global_load_lds((gvoid*)aG1, (lvoid*)aL1, 16, 0, 0);
        __builtin_amdgcn_global_load_lds((gvoid*)aG2, (lvoid*)aL2, 16, 0, 0);
        __builtin_amdgcn_global_load_lds((gvoid*)aG3, (lvoid*)aL3, 16, 0, 0);
        __builtin_amdgcn_global_load_lds((gvoid*)bG0, (lvoid*)bL0, 16, 0, 0);
        __builtin_amdgcn_global_load_lds((gvoid*)bG1, (lvoid*)bL1, 16, 0, 0);
        __builtin_amdgcn_global_load_lds((gvoid*)bG2, (lvoid*)bL2, 16, 0, 0);
        __builtin_amdgcn_global_load_lds((gvoid*)bG3, (lvoid*)bL3, 16, 0, 0);
        aG0 += BK; aG1 += BK; aG2 += BK; aG3 += BK;
        bG0 += BK; bG1 += BK; bG2 += BK; bG3 += BK;
        __syncthreads();   // drains vmcnt(0) before s_barrier

        #pragma unroll
        for (int h = 0; h < 2; h++) {
            const int cg = ((g0 + 4 * h) ^ fsw) * 8;   // un-swizzled ds_read col
            bf16x8 af[4], bfr[4];
            #pragma unroll
            for (int i = 0; i < 4; i++)
                af[i] = *(const bf16x8*)&As[(wm + frow + i * 16) * BK + cg];
            #pragma unroll
            for (int j = 0; j < 4; j++)
                bfr[j] = *(const bf16x8*)&Bs[(wn + frow + j * 16) * BK + cg];

            #pragma unroll
            for (int i = 0; i < 4; i++)
                #pragma unroll
                for (int j = 0; j < 4; j++)
                    acc[i][j] = __builtin_amdgcn_mfma_f32_16x16x32_bf16(
                        af[i], bfr[j], acc[i][j], 0, 0, 0);
        }

        __syncthreads();   // protect LDS before next stage overwrites
    }

    // ---- epilogue: C/D layout col=lane&15, row=(lane>>4)*4+reg (m89/m91)
    const int crow0 = bm * BM + wm + (lane >> 4) * 4;
    const int ccol0 = bn * BN + wn + (lane & 15);

    #pragma unroll
    for (int j = 0; j < 4; j++) {
        const int col = ccol0 + j * 16;
        float bv = bias1[col];
        if (TWO_BIAS) bv += bias2[col];
        #pragma unroll
        for (int i = 0; i < 4; i++) {
            const int row = crow0 + i * 16;
            #pragma unroll
            for (int r = 0; r < 4; r++) {
                float v = acc[i][j][r] + bv;
                if (RELU) v = fmaxf(v, 0.0f);
                if (OUTF32)
                    ((float*)Cp)[(size_t)(row + r) * N + col] = v;
                else
                    ((bf16*)Cp)[(size_t)(row + r) * N + col] = (bf16)v;
            }
        }
    }
}

static inline int cvt_blocks(size_t n) { return (int)((n / 8 + 255) / 256); }

extern "C" void kernel_launch(void* const* d_in, const int* in_sizes, int n_in,
                              void* d_out, int out_size, void* d_ws, size_t ws_size,
                              hipStream_t stream) {
    const float* x       = (const float*)d_in[0];  // [B,S,D_IN] fp32
    const float* W_init  = (const float*)d_in[1];  // [D_H, D_IN] fp32
    const float* b_init  = (const float*)d_in[2];  // [D_H] fp32
    const float* W_ih    = (const float*)d_in[3];  // [D_H, D_H] fp32
    const float* b_ih    = (const float*)d_in[4];  // [D_H] fp32
    const float* b_hh    = (const float*)d_in[5];  // [D_H] fp32
    const float* W_final = (const float*)d_in[6];  // [D_ACT, D_H] fp32
    const float* b_final = (const float*)d_in[7];  // [D_ACT] fp32
    float* out = (float*)d_out;                    // [B,S,D_ACT] fp32

    const int D_H   = in_sizes[2];               // 2048
    const int D_IN  = in_sizes[1] / D_H;         // 1024
    const int D_ACT = in_sizes[7];               // 1024
    const int M     = in_sizes[0] / D_IN;        // B*S = 32768

    const size_t nx  = (size_t)M * D_IN;
    const size_t nw1 = (size_t)D_H * D_IN;
    const size_t nw2 = (size_t)D_H * D_H;
    const size_t nw3 = (size_t)D_ACT * D_H;
    const size_t nh  = (size_t)M * D_H;

    // ws layout: [h: nh*2][a2: nh*2][w1b][w2b][w3b]; xb aliases a2's region
    // (x is dead before layer 2 writes a2 — same-stream ordering).
    char* ws  = (char*)d_ws;
    bf16* h   = (bf16*)ws;
    bf16* a2  = (bf16*)(ws + nh * 2);
    bf16* xb  = a2;                               // alias, see above
    bf16* w1b = (bf16*)(ws + nh * 4);
    bf16* w2b = w1b + nw1;
    bf16* w3b = w2b + nw2;

    cvt_f32_bf16<<<cvt_blocks(nx),  256, 0, stream>>>(x,       xb,  (int)(nx  / 8));
    cvt_f32_bf16<<<cvt_blocks(nw1), 256, 0, stream>>>(W_init,  w1b, (int)(nw1 / 8));
    cvt_f32_bf16<<<cvt_blocks(nw2), 256, 0, stream>>>(W_ih,    w2b, (int)(nw2 / 8));
    cvt_f32_bf16<<<cvt_blocks(nw3), 256, 0, stream>>>(W_final, w3b, (int)(nw3 / 8));

    dim3 blk(256);

    // layer 1: h = relu(x @ W_init^T + b_init)          [bf16 out]
    gemm_bt<1, 0, 0><<<dim3(D_H / BN, M / BM), blk, 0, stream>>>(
        xb, w1b, b_init, nullptr, h, M, D_H, D_IN);

    // layer 2: a2 = relu(h @ W_ih^T + b_ih + b_hh)      [bf16 out]
    gemm_bt<1, 1, 0><<<dim3(D_H / BN, M / BM), blk, 0, stream>>>(
        h, w2b, b_ih, b_hh, a2, M, D_H, D_H);

    // layer 3: out = a2 @ W_final^T + b_final           [fp32 out]
    gemm_bt<0, 0, 1><<<dim3(D_ACT / BN, M / BM), blk, 0, stream>>>(
        a2, w3b, b_final, nullptr, out, M, D_ACT, D_H);
}